// Round 2
// baseline (2849.510 us; speedup 1.0000x reference)
//
#include <hip/hip_runtime.h>

#define NU 200000
#define NI 100000

// Merged destination-row space (users then items):
//   user rows   0      .. NU-1
//   item rows   NU     .. NU+NI-1     (totR = 300000)
// All 6 edge lists histogram/scatter into this one row space, with source
// columns pre-offset (+NU when the source is an item row) so one gather
// table serves every edge. Per-list dest-row bases:
//   l0 u2u     dest user r        base 0
//   l1 u2i f0  dest user r        base 0        (fold0 rows 0..NU/2-1)
//   l2 u2i f1  dest user r+NU/2   base NU/2
//   l3 i2u f0  dest item r        base NU
//   l4 i2u f1  dest item r+NI/2   base NU+NI/2
//   l5 i2i     dest item r        base NU
// col offsets: {0, +NU, +NU, 0, 0, +NU}

#define TOTR (NU + NI)

struct Bld {
  const int* rows[6]; const int* cols[6]; const float* vals[6];
  int nE[6]; int base[6]; int coff[6];
  int* counts; int* cursor;
  uint2* edges;
};

// ---------------- bf16 helpers ----------------

__device__ __forceinline__ unsigned bfr(float f) {  // fp32 -> bf16 bits, RTNE
  unsigned u = __float_as_uint(f);
  return (u + 0x7FFFu + ((u >> 16) & 1u)) >> 16;
}
__device__ __forceinline__ float blo(unsigned p) { return __uint_as_float(p << 16); }
__device__ __forceinline__ float bhi(unsigned p) { return __uint_as_float(p & 0xFFFF0000u); }

// ---------------- CSR build ----------------

__global__ void hist_k(Bld b) {
  int l = blockIdx.y;
  int i = blockIdx.x * blockDim.x + threadIdx.x;
  if (i < b.nE[l]) atomicAdd(&b.counts[b.base[l] + b.rows[l][i]], 1);
}

__global__ void scatter_k(Bld b) {
  int l = blockIdx.y;
  int i = blockIdx.x * blockDim.x + threadIdx.x;
  if (i < b.nE[l]) {
    int r = b.base[l] + b.rows[l][i];
    int p = atomicAdd(&b.cursor[r], 1);
    b.edges[p] = make_uint2((unsigned)(b.cols[l][i] + b.coff[l]),
                            __float_as_uint(b.vals[l][i]));
  }
}

// scanA: per-4096-chunk totals
__global__ __launch_bounds__(256) void scanA_k(const int* __restrict__ counts,
                                               int* __restrict__ bsum, int n) {
  int t = threadIdx.x;
  int i0 = blockIdx.x * 4096 + t * 16;
  int s = 0;
#pragma unroll
  for (int i = 0; i < 16; ++i) { int idx = i0 + i; if (idx < n) s += counts[idx]; }
#pragma unroll
  for (int o = 1; o < 64; o <<= 1) s += __shfl_xor(s, o, 64);
  __shared__ int ws[4];
  if ((t & 63) == 0) ws[t >> 6] = s;
  __syncthreads();
  if (t == 0) bsum[blockIdx.x] = ws[0] + ws[1] + ws[2] + ws[3];
}

// scanB: exclusive scan of chunk totals (single block), writes grand total
__global__ __launch_bounds__(256) void scanB_k(int* __restrict__ bsum,
                                               int* __restrict__ offs, int nb, int n) {
  __shared__ int s_run;
  __shared__ int wsum[4];
  int t = threadIdx.x, lane = t & 63, wv = t >> 6;
  if (t == 0) s_run = 0;
  __syncthreads();
  for (int base = 0; base < nb; base += 256) {
    int v = (base + t < nb) ? bsum[base + t] : 0;
    int sc = v;
#pragma unroll
    for (int o = 1; o < 64; o <<= 1) { int x = __shfl_up(sc, o, 64); if (lane >= o) sc += x; }
    if (lane == 63) wsum[wv] = sc;
    __syncthreads();
    int wb = 0;
    for (int j = 0; j < wv; ++j) wb += wsum[j];
    int run = s_run;
    if (base + t < nb) bsum[base + t] = run + wb + sc - v;
    __syncthreads();
    if (t == 255) s_run = run + wsum[0] + wsum[1] + wsum[2] + wsum[3];
    __syncthreads();
  }
  if (t == 0) { bsum[nb] = s_run; offs[n] = s_run; }
}

// scanC: full exclusive scan, offs + cursor
__global__ __launch_bounds__(256) void scanC_k(const int* __restrict__ counts,
    const int* __restrict__ bsum, int* __restrict__ offs, int* __restrict__ cursor, int n) {
  int t = threadIdx.x, lane = t & 63, wv = t >> 6;
  int i0 = blockIdx.x * 4096 + t * 16;
  int v[16];
  int s = 0;
#pragma unroll
  for (int i = 0; i < 16; ++i) {
    int idx = i0 + i;
    int c = (idx < n) ? counts[idx] : 0;
    s += c; v[i] = s;
  }
  int tot = s, sc = tot;
#pragma unroll
  for (int o = 1; o < 64; o <<= 1) { int x = __shfl_up(sc, o, 64); if (lane >= o) sc += x; }
  __shared__ int wsum[4];
  if (lane == 63) wsum[wv] = sc;
  __syncthreads();
  int wb = 0;
  for (int j = 0; j < wv; ++j) wb += wsum[j];
  int ebase = bsum[blockIdx.x] + wb + (sc - tot);
#pragma unroll
  for (int i = 0; i < 16; ++i) {
    int idx = i0 + i;
    if (idx < n) {
      int pv = ebase + (i ? v[i - 1] : 0);
      offs[idx] = pv; cursor[idx] = pv;
    }
  }
}

// ---------------- init: fp32 embs [4][N][64] -> bf16 buf [N][256] ----------------

__global__ __launch_bounds__(256) void init_k(const float* __restrict__ embs,
                                              uint2* __restrict__ buf, int nrows) {
  int idx = blockIdx.x * 256 + threadIdx.x;  // one uint2 (4 elems) per thread
  if (idx >= nrows * 64) return;
  int u = idx >> 6, q = idx & 63;
  int k = q >> 4, d = (q & 15) * 4;
  const float4 f = *(const float4*)(embs + ((size_t)k * nrows + u) * 64 + d);
  uint2 o;
  o.x = (bfr(f.y) << 16) | bfr(f.x);
  o.y = (bfr(f.w) << 16) | bfr(f.z);
  buf[idx] = o;
}

// ---------------- pull-mode SpMM over bf16 rows ----------------
// Batch-16 gathers, zero-padded: lanes >= nn hold (col=0, val=0); the padded
// gathers all hit row 0 (one hot line) and val=0 makes the FMA a no-op.
// No scalar tail -> no per-edge full-latency drains on short rows.

__device__ __forceinline__ void gacc(float a[4], const uint2* __restrict__ x,
    int beg, int end, const uint2* __restrict__ edges, int lane) {
  for (int e0 = beg; e0 < end; e0 += 64) {
    int nn = min(64, end - e0);
    uint2 ev = make_uint2(0u, 0u);
    if (lane < nn) ev = edges[e0 + lane];
    int nb = (nn + 15) & ~15;
    for (int s = 0; s < nb; s += 16) {
      uint2 d[16];
#pragma unroll
      for (int j = 0; j < 16; ++j) {
        unsigned c = (unsigned)__shfl((int)ev.x, s + j);
        d[j] = x[(size_t)c * 64u + (unsigned)lane];
      }
#pragma unroll
      for (int j = 0; j < 16; ++j) {
        float v = __uint_as_float((unsigned)__shfl((int)ev.y, s + j));
        a[0] += v * blo(d[j].x);
        a[1] += v * bhi(d[j].x);
        a[2] += v * blo(d[j].y);
        a[3] += v * bhi(d[j].y);
      }
    }
  }
}

__global__ __launch_bounds__(256) void spmm_k(
    const uint2* __restrict__ x, uint2* __restrict__ nxt,
    const int* __restrict__ offs, const uint2* __restrict__ edges, int nrows) {
  int w = (blockIdx.x * 256 + threadIdx.x) >> 6;
  int lane = threadIdx.x & 63;
  if (w >= nrows) return;
  float a[4] = {0.f, 0.f, 0.f, 0.f};
  gacc(a, x, offs[w], offs[w + 1], edges, lane);
  uint2 o;
  o.x = (bfr(a[1]) << 16) | bfr(a[0]);
  o.y = (bfr(a[3]) << 16) | bfr(a[2]);
  nxt[(size_t)w * 64 + lane] = o;
}

// ---------------- final: out = relu(((e0 + l1 + l2)/3) @ W_k) ----------------

__global__ __launch_bounds__(256) void xform_k(float* __restrict__ out,
    const float* __restrict__ uembs, const float* __restrict__ iembs,
    const uint2* __restrict__ u1, const uint2* __restrict__ u0,
    const uint2* __restrict__ i1, const uint2* __restrict__ i0,
    const float* __restrict__ Wu, const float* __restrict__ Wv) {
  const int utiles = NU / 64;  // 3125
  int tile = blockIdx.x;
  const float* embs; const uint2 *b1, *b0; const float* W; float* base; int nrows, row0;
  if (tile < utiles) {
    embs = uembs; b1 = u1; b0 = u0; W = Wu; base = out; nrows = NU; row0 = tile * 64;
  } else {
    embs = iembs; b1 = i1; b0 = i0; W = Wv; base = out + (size_t)NU * 256; nrows = NI;
    row0 = (tile - utiles) * 64;
  }
  __shared__ float Xs[64][68];
  __shared__ float Ws[64][68];
  int t = threadIdx.x;
  int tr = t >> 4, tc = (t & 15) * 4;
  const float inv3 = 1.f / 3.f;
  for (int k = 0; k < 4; ++k) {
#pragma unroll
    for (int i = 0; i < 4; ++i) {
      int e = t + i * 256;  // 0..1023 float4-slots over the 64x64 tile
      int r = e >> 4, c4 = e & 15;
      float4 wv = ((const float4*)(W + (size_t)k * 4096 + (size_t)r * 64))[c4];
      *(float4*)&Ws[r][c4 * 4] = wv;
      int row = row0 + r;
      float4 xv = make_float4(0.f, 0.f, 0.f, 0.f);
      if (row < nrows) {
        const float4 e0 = *(const float4*)(embs + ((size_t)k * nrows + row) * 64 + c4 * 4);
        uint2 p1 = b1[(size_t)row * 64 + k * 16 + c4];
        uint2 p2 = b0[(size_t)row * 64 + k * 16 + c4];
        xv.x = (e0.x + blo(p1.x) + blo(p2.x)) * inv3;
        xv.y = (e0.y + bhi(p1.x) + bhi(p2.x)) * inv3;
        xv.z = (e0.z + blo(p1.y) + blo(p2.y)) * inv3;
        xv.w = (e0.w + bhi(p1.y) + bhi(p2.y)) * inv3;
      }
      *(float4*)&Xs[r][c4 * 4] = xv;
    }
    __syncthreads();
    float y[4][4];
#pragma unroll
    for (int i = 0; i < 4; ++i)
#pragma unroll
      for (int j = 0; j < 4; ++j) y[i][j] = 0.f;
    for (int j = 0; j < 64; ++j) {
      float xr[4], wc[4];
#pragma unroll
      for (int i = 0; i < 4; ++i) { xr[i] = Xs[tr * 4 + i][j]; wc[i] = Ws[j][tc + i]; }
#pragma unroll
      for (int i = 0; i < 4; ++i)
#pragma unroll
        for (int jj = 0; jj < 4; ++jj) y[i][jj] += xr[i] * wc[jj];
    }
#pragma unroll
    for (int i = 0; i < 4; ++i) {
      int row = row0 + tr * 4 + i;
      if (row < nrows) {
        float4 o = make_float4(fmaxf(y[i][0], 0.f), fmaxf(y[i][1], 0.f),
                               fmaxf(y[i][2], 0.f), fmaxf(y[i][3], 0.f));
        ((float4*)(base + (size_t)row * 256 + k * 64))[t & 15] = o;
      }
    }
    __syncthreads();
  }
}

// ---------------- driver ----------------

extern "C" void kernel_launch(void* const* d_in, const int* in_sizes, int n_in,
                              void* d_out, int out_size, void* d_ws, size_t ws_size,
                              hipStream_t stream) {
  Bld b;
  const int rows_idx[6] = {0, 3, 6, 9, 12, 15};
  const int dbase[6] = {0, 0, NU / 2, NU, NU + NI / 2, NU};
  const int coff[6]  = {0, NU, NU, 0, 0, NU};
  size_t totE = 0;
  for (int l = 0; l < 6; ++l) {
    b.rows[l] = (const int*)d_in[rows_idx[l]];
    b.cols[l] = (const int*)d_in[rows_idx[l] + 1];
    b.vals[l] = (const float*)d_in[rows_idx[l] + 2];
    b.nE[l] = in_sizes[rows_idx[l]];
    b.base[l] = dbase[l];
    b.coff[l] = coff[l];
    totE += (size_t)b.nE[l];
  }
  const int totR = TOTR;  // 300000 merged destination rows
  const int nb = (totR + 4095) / 4096;

  char* basep = (char*)d_ws; size_t off = 0;
  auto alloc = [&](size_t bytes) -> void* {
    void* r = basep + off; off = (off + bytes + 255) & ~(size_t)255; return r;
  };
  uint2* bufA = (uint2*)alloc((size_t)TOTR * 64 * 8);  // users rows 0.., items rows NU..
  uint2* bufB = (uint2*)alloc((size_t)TOTR * 64 * 8);
  int* counts = (int*)alloc((size_t)totR * 4);
  int* offs = (int*)alloc((size_t)(totR + 1) * 4);
  int* cursor = (int*)alloc((size_t)totR * 4);
  int* bsum = (int*)alloc((size_t)(nb + 1) * 4);
  uint2* edges = (uint2*)alloc(totE * 8);
  b.counts = counts; b.cursor = cursor; b.edges = edges;

  hipMemsetAsync(counts, 0, (size_t)totR * 4, stream);
  int maxE = 0;
  for (int l = 0; l < 6; ++l) if (b.nE[l] > maxE) maxE = b.nE[l];
  dim3 eg((maxE + 255) / 256, 6);
  hist_k<<<eg, 256, 0, stream>>>(b);
  scanA_k<<<nb, 256, 0, stream>>>(counts, bsum, totR);
  scanB_k<<<1, 256, 0, stream>>>(bsum, offs, nb, totR);
  scanC_k<<<nb, 256, 0, stream>>>(counts, bsum, offs, cursor, totR);
  scatter_k<<<eg, 256, 0, stream>>>(b);

  const float* user_embs = (const float*)d_in[18];
  const float* item_embs = (const float*)d_in[19];
  const float* W_u = (const float*)d_in[20];
  const float* W_v = (const float*)d_in[21];

  init_k<<<(NU * 64 + 255) / 256, 256, 0, stream>>>(user_embs, bufA, NU);
  init_k<<<(NI * 64 + 255) / 256, 256, 0, stream>>>(item_embs, bufA + (size_t)NU * 64, NI);

  // layer 1: read bufA -> write bufB; layer 2: read bufB -> write bufA
  spmm_k<<<(TOTR + 3) / 4, 256, 0, stream>>>(bufA, bufB, offs, edges, TOTR);
  spmm_k<<<(TOTR + 3) / 4, 256, 0, stream>>>(bufB, bufA, offs, edges, TOTR);

  int tiles = NU / 64 + (NI + 63) / 64;
  xform_k<<<tiles, 256, 0, stream>>>((float*)d_out, user_embs, item_embs,
      bufB, bufA, bufB + (size_t)NU * 64, bufA + (size_t)NU * 64, W_u, W_v);
}

// Round 3
// 2173.753 us; speedup vs baseline: 1.3109x; 1.3109x over previous
//
#include <hip/hip_runtime.h>

#define NU 200000
#define NI 100000
#define TOTR (NU + NI)   // merged dest rows: users 0..NU-1, items NU..NU+NI-1
#define NBK 586          // ceil(TOTR/512) row-buckets of 512 rows
#define EPB 8192         // edges per block in build kernels (32/thread)

// Per-list dest-row bases and source-column offsets (merged row space):
//   l0 u2u     dest r        col +0
//   l1 u2i f0  dest r        col +NU
//   l2 u2i f1  dest r+NU/2   col +NU
//   l3 i2u f0  dest NU+r     col +0
//   l4 i2u f1  dest NU+NI/2+r col +0
//   l5 i2i     dest NU+r     col +NU

struct Bld {
  const int* rows[6]; const int* cols[6]; const float* vals[6];
  int base[6]; int coff[6];
  int eoff[7];  // exclusive prefix of edge counts over the 6 lists
};

// ---------------- bf16 helpers ----------------

__device__ __forceinline__ unsigned bfr(float f) {  // fp32 -> bf16 bits, RTNE
  unsigned u = __float_as_uint(f);
  return (u + 0x7FFFu + ((u >> 16) & 1u)) >> 16;
}
__device__ __forceinline__ float blo(unsigned p) { return __uint_as_float(p << 16); }
__device__ __forceinline__ float bhi(unsigned p) { return __uint_as_float(p & 0xFFFF0000u); }

__device__ __forceinline__ int list_of(const Bld& b, int g) {
  int l = 0;
#pragma unroll
  for (int k = 0; k < 5; ++k) l += (g >= b.eoff[k + 1]) ? 1 : 0;
  return l;
}

// ---------------- bucketed CSR build ----------------

// Pass 1: bucket histogram (LDS-aggregated; reads rows only)
__global__ __launch_bounds__(256) void bhist_k(Bld b, int* __restrict__ bcount, int totE) {
  __shared__ int cnt[NBK];
  int t = threadIdx.x;
  for (int i = t; i < NBK; i += 256) cnt[i] = 0;
  __syncthreads();
  int g0 = blockIdx.x * EPB;
  int gend = min(g0 + EPB, totE);
  for (int g = g0 + t; g < gend; g += 256) {
    int l = list_of(b, g);
    int i = g - b.eoff[l];
    int drow = b.base[l] + b.rows[l][i];
    atomicAdd(&cnt[drow >> 9], 1);
  }
  __syncthreads();
  for (int i = t; i < NBK; i += 256) if (cnt[i]) atomicAdd(&bcount[i], cnt[i]);
}

// Pass 2: exclusive scan of 586 bucket counts -> bbase, bcursor; offs[TOTR]=totE
__global__ __launch_bounds__(256) void bscan_k(const int* __restrict__ bcount,
    int* __restrict__ bbase, int* __restrict__ bcursor, int* __restrict__ offs) {
  __shared__ int s_run;
  __shared__ int wsum[4];
  int t = threadIdx.x, lane = t & 63, wv = t >> 6;
  if (t == 0) s_run = 0;
  __syncthreads();
  for (int base = 0; base < NBK; base += 256) {
    int v = (base + t < NBK) ? bcount[base + t] : 0;
    int sc = v;
#pragma unroll
    for (int o = 1; o < 64; o <<= 1) { int x = __shfl_up(sc, o, 64); if (lane >= o) sc += x; }
    if (lane == 63) wsum[wv] = sc;
    __syncthreads();
    int wb = 0;
    for (int j = 0; j < wv; ++j) wb += wsum[j];
    int run = s_run;
    if (base + t < NBK) {
      int ex = run + wb + sc - v;
      bbase[base + t] = ex; bcursor[base + t] = ex;
    }
    __syncthreads();
    if (t == 255) s_run = run + wsum[0] + wsum[1] + wsum[2] + wsum[3];
    __syncthreads();
  }
  if (t == 0) { bbase[NBK] = s_run; offs[TOTR] = s_run; }
}

// Pass 3: block-binned scatter into bucket-major ebuf.
// Each block: LDS per-bucket count (atomic return = local pos), one global
// atomic per bucket reserves a contiguous range, then contiguous-run writes.
// ebuf entry: x = (rowLocal<<19) | (col + coff)  [9+19 bits], y = val bits.
__global__ __launch_bounds__(256) void bscatter_k(Bld b, int* __restrict__ bcursor,
    uint2* __restrict__ ebuf, int totE) {
  __shared__ int cnt[NBK];
  __shared__ int gb[NBK];
  int t = threadIdx.x;
  for (int i = t; i < NBK; i += 256) cnt[i] = 0;
  __syncthreads();
  int g0 = blockIdx.x * EPB;
  int gend = min(g0 + EPB, totE);
  unsigned pk[32];  // (bucket<<22)|(rowLocal<<13)|localPos   10+9+13 bits
  for (int j = 0; j < 32; ++j) {
    int g = g0 + t + j * 256;
    if (g < gend) {
      int l = list_of(b, g);
      int i = g - b.eoff[l];
      int drow = b.base[l] + b.rows[l][i];
      int bk = drow >> 9, rl = drow & 511;
      int lp = atomicAdd(&cnt[bk], 1);
      pk[j] = ((unsigned)bk << 22) | ((unsigned)rl << 13) | (unsigned)lp;
    }
  }
  __syncthreads();
  for (int i = t; i < NBK; i += 256) {
    int c = cnt[i];
    if (c) gb[i] = atomicAdd(&bcursor[i], c);
  }
  __syncthreads();
  for (int j = 0; j < 32; ++j) {
    int g = g0 + t + j * 256;
    if (g >= gend) break;
    unsigned v = pk[j];
    int bk = v >> 22, rl = (v >> 13) & 511, lp = v & 0x1FFF;
    int l = list_of(b, g);
    int i = g - b.eoff[l];
    unsigned cc = (unsigned)(b.cols[l][i] + b.coff[l]);
    ebuf[gb[bk] + lp] = make_uint2(((unsigned)rl << 19) | cc,
                                   __float_as_uint(b.vals[l][i]));
  }
}

// Pass 4: one block per bucket. Row counts + exclusive scan in LDS -> offs,
// then permute bucket edges (L2-resident ~170KB window) into final CSR order.
__global__ __launch_bounds__(256) void fine_k(const uint2* __restrict__ ebuf,
    const int* __restrict__ bbase, int* __restrict__ offs,
    uint2* __restrict__ edges) {
  __shared__ int rcnt[512];
  __shared__ int rcur[512];
  __shared__ int wsum[4];
  int bk = blockIdx.x, t = threadIdx.x;
  rcnt[t] = 0; rcnt[t + 256] = 0;
  __syncthreads();
  int gbeg = bbase[bk], gend = bbase[bk + 1];
  for (int e = gbeg + t; e < gend; e += 256)
    atomicAdd(&rcnt[ebuf[e].x >> 19], 1);
  __syncthreads();
  int a0 = rcnt[2 * t], a1 = rcnt[2 * t + 1];
  int ts = a0 + a1, sc = ts;
  int lane = t & 63, wv = t >> 6;
#pragma unroll
  for (int o = 1; o < 64; o <<= 1) { int x = __shfl_up(sc, o, 64); if (lane >= o) sc += x; }
  if (lane == 63) wsum[wv] = sc;
  __syncthreads();
  int wb = 0;
  for (int j = 0; j < wv; ++j) wb += wsum[j];
  int ex = wb + sc - ts;
  __syncthreads();  // all rcnt reads complete before overwrite
  rcnt[2 * t] = ex;      rcnt[2 * t + 1] = ex + a0;
  rcur[2 * t] = ex;      rcur[2 * t + 1] = ex + a0;
  __syncthreads();
  int rfirst = bk << 9;
  for (int i = t; i < 512; i += 256) {
    int row = rfirst + i;
    if (row < TOTR) offs[row] = gbeg + rcnt[i];
  }
  for (int e = gbeg + t; e < gend; e += 256) {
    uint2 ev = ebuf[e];
    int rl = ev.x >> 19;
    int lp = atomicAdd(&rcur[rl], 1);
    edges[gbeg + lp] = make_uint2(ev.x & 0x7FFFFu, ev.y);
  }
}

// ---------------- init: fp32 embs [4][N][64] -> bf16 buf [N][256] ----------------

__global__ __launch_bounds__(256) void init_k(const float* __restrict__ embs,
                                              uint2* __restrict__ buf, int nrows) {
  int idx = blockIdx.x * 256 + threadIdx.x;  // one uint2 (4 elems) per thread
  if (idx >= nrows * 64) return;
  int u = idx >> 6, q = idx & 63;
  int k = q >> 4, d = (q & 15) * 4;
  const float4 f = *(const float4*)(embs + ((size_t)k * nrows + u) * 64 + d);
  uint2 o;
  o.x = (bfr(f.y) << 16) | bfr(f.x);
  o.y = (bfr(f.w) << 16) | bfr(f.z);
  buf[idx] = o;
}

// ---------------- pull-mode SpMM over bf16 rows ----------------
// Batch-16 gathers, zero-padded: lanes >= nn hold (col=0, val=0); padded
// gathers all hit row 0 (one hot line) and val=0 makes the FMA a no-op.

__device__ __forceinline__ void gacc(float a[4], const uint2* __restrict__ x,
    int beg, int end, const uint2* __restrict__ edges, int lane) {
  for (int e0 = beg; e0 < end; e0 += 64) {
    int nn = min(64, end - e0);
    uint2 ev = make_uint2(0u, 0u);
    if (lane < nn) ev = edges[e0 + lane];
    int nb = (nn + 15) & ~15;
    for (int s = 0; s < nb; s += 16) {
      uint2 d[16];
#pragma unroll
      for (int j = 0; j < 16; ++j) {
        unsigned c = (unsigned)__shfl((int)ev.x, s + j);
        d[j] = x[(size_t)c * 64u + (unsigned)lane];
      }
#pragma unroll
      for (int j = 0; j < 16; ++j) {
        float v = __uint_as_float((unsigned)__shfl((int)ev.y, s + j));
        a[0] += v * blo(d[j].x);
        a[1] += v * bhi(d[j].x);
        a[2] += v * blo(d[j].y);
        a[3] += v * bhi(d[j].y);
      }
    }
  }
}

__global__ __launch_bounds__(256) void spmm_k(
    const uint2* __restrict__ x, uint2* __restrict__ nxt,
    const int* __restrict__ offs, const uint2* __restrict__ edges, int nrows) {
  int w = (blockIdx.x * 256 + threadIdx.x) >> 6;
  int lane = threadIdx.x & 63;
  if (w >= nrows) return;
  float a[4] = {0.f, 0.f, 0.f, 0.f};
  gacc(a, x, offs[w], offs[w + 1], edges, lane);
  uint2 o;
  o.x = (bfr(a[1]) << 16) | bfr(a[0]);
  o.y = (bfr(a[3]) << 16) | bfr(a[2]);
  nxt[(size_t)w * 64 + lane] = o;
}

// ---------------- final: out = relu(((e0 + l1 + l2)/3) @ W_k) ----------------

__global__ __launch_bounds__(256) void xform_k(float* __restrict__ out,
    const float* __restrict__ uembs, const float* __restrict__ iembs,
    const uint2* __restrict__ u1, const uint2* __restrict__ u0,
    const uint2* __restrict__ i1, const uint2* __restrict__ i0,
    const float* __restrict__ Wu, const float* __restrict__ Wv) {
  const int utiles = NU / 64;  // 3125
  int tile = blockIdx.x;
  const float* embs; const uint2 *b1, *b0; const float* W; float* base; int nrows, row0;
  if (tile < utiles) {
    embs = uembs; b1 = u1; b0 = u0; W = Wu; base = out; nrows = NU; row0 = tile * 64;
  } else {
    embs = iembs; b1 = i1; b0 = i0; W = Wv; base = out + (size_t)NU * 256; nrows = NI;
    row0 = (tile - utiles) * 64;
  }
  __shared__ float Xs[64][68];
  __shared__ float Ws[64][68];
  int t = threadIdx.x;
  int tr = t >> 4, tc = (t & 15) * 4;
  const float inv3 = 1.f / 3.f;
  for (int k = 0; k < 4; ++k) {
#pragma unroll
    for (int i = 0; i < 4; ++i) {
      int e = t + i * 256;  // 0..1023 float4-slots over the 64x64 tile
      int r = e >> 4, c4 = e & 15;
      float4 wv = ((const float4*)(W + (size_t)k * 4096 + (size_t)r * 64))[c4];
      *(float4*)&Ws[r][c4 * 4] = wv;
      int row = row0 + r;
      float4 xv = make_float4(0.f, 0.f, 0.f, 0.f);
      if (row < nrows) {
        const float4 e0 = *(const float4*)(embs + ((size_t)k * nrows + row) * 64 + c4 * 4);
        uint2 p1 = b1[(size_t)row * 64 + k * 16 + c4];
        uint2 p2 = b0[(size_t)row * 64 + k * 16 + c4];
        xv.x = (e0.x + blo(p1.x) + blo(p2.x)) * inv3;
        xv.y = (e0.y + bhi(p1.x) + bhi(p2.x)) * inv3;
        xv.z = (e0.z + blo(p1.y) + blo(p2.y)) * inv3;
        xv.w = (e0.w + bhi(p1.y) + bhi(p2.y)) * inv3;
      }
      *(float4*)&Xs[r][c4 * 4] = xv;
    }
    __syncthreads();
    float y[4][4];
#pragma unroll
    for (int i = 0; i < 4; ++i)
#pragma unroll
      for (int j = 0; j < 4; ++j) y[i][j] = 0.f;
    for (int j = 0; j < 64; ++j) {
      float xr[4], wc[4];
#pragma unroll
      for (int i = 0; i < 4; ++i) { xr[i] = Xs[tr * 4 + i][j]; wc[i] = Ws[j][tc + i]; }
#pragma unroll
      for (int i = 0; i < 4; ++i)
#pragma unroll
        for (int jj = 0; jj < 4; ++jj) y[i][jj] += xr[i] * wc[jj];
    }
#pragma unroll
    for (int i = 0; i < 4; ++i) {
      int row = row0 + tr * 4 + i;
      if (row < nrows) {
        float4 o = make_float4(fmaxf(y[i][0], 0.f), fmaxf(y[i][1], 0.f),
                               fmaxf(y[i][2], 0.f), fmaxf(y[i][3], 0.f));
        ((float4*)(base + (size_t)row * 256 + k * 64))[t & 15] = o;
      }
    }
    __syncthreads();
  }
}

// ---------------- driver ----------------

extern "C" void kernel_launch(void* const* d_in, const int* in_sizes, int n_in,
                              void* d_out, int out_size, void* d_ws, size_t ws_size,
                              hipStream_t stream) {
  Bld b;
  const int rows_idx[6] = {0, 3, 6, 9, 12, 15};
  const int dbase[6] = {0, 0, NU / 2, NU, NU + NI / 2, NU};
  const int coff[6]  = {0, NU, NU, 0, 0, NU};
  int totE = 0;
  for (int l = 0; l < 6; ++l) {
    b.rows[l] = (const int*)d_in[rows_idx[l]];
    b.cols[l] = (const int*)d_in[rows_idx[l] + 1];
    b.vals[l] = (const float*)d_in[rows_idx[l] + 2];
    b.base[l] = dbase[l];
    b.coff[l] = coff[l];
    b.eoff[l] = totE;
    totE += in_sizes[rows_idx[l]];
  }
  b.eoff[6] = totE;

  char* basep = (char*)d_ws; size_t off = 0;
  auto alloc = [&](size_t bytes) -> void* {
    void* r = basep + off; off = (off + bytes + 255) & ~(size_t)255; return r;
  };
  uint2* bufA = (uint2*)alloc((size_t)TOTR * 64 * 8);  // users rows 0.., items rows NU..
  uint2* bufB = (uint2*)alloc((size_t)TOTR * 64 * 8);
  int* offs = (int*)alloc((size_t)(TOTR + 1) * 4);
  int* bcount = (int*)alloc((size_t)NBK * 4);
  int* bbase = (int*)alloc((size_t)(NBK + 1) * 4);
  int* bcursor = (int*)alloc((size_t)NBK * 4);
  uint2* edges = (uint2*)alloc((size_t)totE * 8);
  uint2* ebuf = bufB;  // bufB is free during the build phase (67MB < 153MB)

  hipMemsetAsync(bcount, 0, (size_t)NBK * 4, stream);
  int nblk = (totE + EPB - 1) / EPB;
  bhist_k<<<nblk, 256, 0, stream>>>(b, bcount, totE);
  bscan_k<<<1, 256, 0, stream>>>(bcount, bbase, bcursor, offs);
  bscatter_k<<<nblk, 256, 0, stream>>>(b, bcursor, ebuf, totE);
  fine_k<<<NBK, 256, 0, stream>>>(ebuf, bbase, offs, edges);

  const float* user_embs = (const float*)d_in[18];
  const float* item_embs = (const float*)d_in[19];
  const float* W_u = (const float*)d_in[20];
  const float* W_v = (const float*)d_in[21];

  init_k<<<(NU * 64 + 255) / 256, 256, 0, stream>>>(user_embs, bufA, NU);
  init_k<<<(NI * 64 + 255) / 256, 256, 0, stream>>>(item_embs, bufA + (size_t)NU * 64, NI);

  // layer 1: read bufA -> write bufB (overwrites consumed ebuf); layer 2: bufB -> bufA
  spmm_k<<<(TOTR + 3) / 4, 256, 0, stream>>>(bufA, bufB, offs, edges, TOTR);
  spmm_k<<<(TOTR + 3) / 4, 256, 0, stream>>>(bufB, bufA, offs, edges, TOTR);

  int tiles = NU / 64 + (NI + 63) / 64;
  xform_k<<<tiles, 256, 0, stream>>>((float*)d_out, user_embs, item_embs,
      bufB, bufA, bufB + (size_t)NU * 64, bufA + (size_t)NU * 64, W_u, W_v);
}